// Round 5
// baseline (174.609 us; speedup 1.0000x reference)
//
#include <hip/hip_runtime.h>

// NCC loss, fully fused, R5: lane-balanced wave-private pipeline.
// w-stage: both slices in ONE 48-lane round. h-stage: 64-lane round + 16-lane
// remainder. Ring: shift-by-2 per macro (SA/SB), hoisted to iteration top to
// overlap w-stage. One lgkmcnt(0) per macro; wsum/hsum double-buffered.
// Vols: [B=2][D=160][H=192][W=160] fp32. Out: scalar -mean(cc).

#define B_    2
#define D_    160
#define H_    192
#define W_    160
#define HW_   (H_*W_)
#define SSTR  28
#define SSLC  (24*SSTR)            // 672
#define OFF_J (2*SSLC)             // 1344: raw J slices base
#define OFF_WS 2688
#define WFS   484                  // wsum field stride = 24*20+4
#define WSLC5 (5*WFS)              // 2420: per-slice wsum buffer
#define OFF_HS (OFF_WS + 2*WSLC5)  // 7528
#define HFS   324                  // hsum field stride = 16*20+4
#define HSLC5 (5*HFS)              // 1620: per-slice hsum buffer
#define OFF_RED (OFF_HS + 2*HSLC5) // 10768
#define SMEM_TOT (OFF_RED + 8)     // 10776 dw = 43.1 KB -> 3 blocks/CU
#define DC    40
#define NMAC  24                   // (DC+8)/2
#define W3I   (1.0f/729.0f)
#define NTOT  9830400.0f

#if __has_builtin(__builtin_amdgcn_rcpf)
#define RCP(x) __builtin_amdgcn_rcpf(x)
#else
#define RCP(x) (1.0f/(x))
#endif

#define LGKM0() asm volatile("s_waitcnt lgkmcnt(0)" ::: "memory")

// sliding 9-window along w: 12 inputs -> 4 outputs as one float4
#define SLIDEX(EXPR, F) { \
  float v_[12]; \
  _Pragma("unroll") for (int k_ = 0; k_ < 12; ++k_) { v_[k_] = (EXPR); } \
  float s_ = v_[0]+v_[1]+v_[2]+v_[3]+v_[4]+v_[5]+v_[6]+v_[7]+v_[8]; \
  float4 o_; o_.x = s_; s_ += v_[9]-v_[0]; o_.y = s_; \
  s_ += v_[10]-v_[1]; o_.z = s_; s_ += v_[11]-v_[2]; o_.w = s_; \
  *(float4*)&sm[wwr + (F)*WFS] = o_; }

__global__ __launch_bounds__(256, 3) void ncc_fused(const float* __restrict__ gI,
                                                    const float* __restrict__ gJ,
                                                    float* __restrict__ out)
{
  __shared__ __align__(16) float sm[SMEM_TOT];
  const int tid  = threadIdx.x;
  const int lane = tid & 63;
  const int Q    = tid >> 6;           // wave id = w-quad owner
  const int w0   = blockIdx.x * 16;
  const int h0   = blockIdx.y * 16;
  const int bz   = blockIdx.z;
  const int bb   = bz >> 2;
  const int d_lo = (bz & 3) * DC;

  // zero raw region once; invalid-hw slots stay 0 = 'same' zero pad
  for (int i = tid; i < OFF_WS; i += 256) sm[i] = 0.f;

  // ---------- staging task precompute: 288 tasks = 2 slc x 24 r x 6 quads ----
  bool val0 = false, val1 = false;
  int  lds0 = 0, lds1 = 0, slc0 = 0, slc1 = 0;
  const float *pi0 = gI, *pj0 = gJ, *pi1 = gI, *pj1 = gJ;
  {
    const int tA = tid;
    const int tB = (tid >= 224) ? (tid + 32) : 512;  // wave 3 takes 256..287
    auto prep = [&](int t, bool& val, int& lo, int& slc,
                    const float*& pi, const float*& pj) {
      if (t >= 288) { val = false; return; }
      slc = t / 144;
      const int u = t - slc*144;
      const int r = u / 6, c = u - r*6;
      const int gh = h0 - 4 + r;
      const int gw = w0 - 4 + 4*c;
      val = ((unsigned)gh < (unsigned)H_) && (gw >= 0) && (gw + 3 < W_);
      lo  = slc*SSLC + r*SSTR + 4*c;
      const long off = ((long)(bb*D_ + (d_lo - 4 + slc))*H_ + gh)*(long)W_ + gw;
      pi = gI + off; pj = gJ + off;
    };
    prep(tA, val0, lds0, slc0, pi0, pj0);
    prep(tB, val1, lds1, slc1, pi1, pj1);
  }

  // ---------- w-stage: 48 lanes = 2 slices x 24 rows, one round ----------
  const bool wact = (lane < 48);
  const int  wslc = lane / 24;
  const int  wrow = lane - wslc*24;
  const int  wrd  = wslc*SSLC + wrow*SSTR + 4*Q;          // +OFF_J for J
  const int  wwr  = OFF_WS + wslc*WSLC5 + wrow*20 + 4*Q;  // + f*WFS

  // ---------- h-stage: 80 tasks = 2 slc x 5 f x 2 half x 4 wq ----------
  auto prep_h = [&](int t, int& rd, int& wr) {
    const int wq   = t & 3;
    const int f    = (t >> 2) % 5;
    const int half = (t / 20) & 1;
    const int slc  = t / 40;
    rd = OFF_WS + slc*WSLC5 + f*WFS + half*160 + 4*Q + wq;  // + k*20
    wr = OFF_HS + slc*HSLC5 + f*HFS + half*160 + 4*Q + wq;  // + j*20
  };
  int h1rd, h1wr, h2rd = 0, h2wr = 0;
  prep_h(lane, h1rd, h1wr);                 // t = 0..63 (all < 80, full wave)
  const bool hact2 = (lane < 16);
  if (hact2) prep_h(lane + 64, h2rd, h2wr); // t = 64..79

  // ---------- ring: lane -> (rh = lane>>2, wq = lane&3) ----------
  const int rh = lane >> 2, rwq = lane & 3;
  const int hbA = OFF_HS + rh*20 + 4*Q + rwq;   // + f*HFS ; slice A buf
  const int hbB = hbA + HSLC5;                  // slice B buf

  float ring[5][9], S[5];
  #pragma unroll
  for (int f = 0; f < 5; ++f) {
    S[f] = 0.f;
    #pragma unroll
    for (int k = 0; k < 9; ++k) ring[f][k] = 0.f;
  }
  float acc = 0.f;

  // ---------- global prefetch ----------
  float4 f0i = {0,0,0,0}, f0j = {0,0,0,0}, f1i = {0,0,0,0}, f1j = {0,0,0,0};
  auto fetch = [&](int sbase) {
    if (val0 && (unsigned)(sbase + slc0) < (unsigned)D_) {
      f0i = *(const float4*)pi0; f0j = *(const float4*)pj0;
    } else { f0i = make_float4(0,0,0,0); f0j = make_float4(0,0,0,0); }
    pi0 += 2*HW_; pj0 += 2*HW_;
    if (val1 && (unsigned)(sbase + slc1) < (unsigned)D_) {
      f1i = *(const float4*)pi1; f1j = *(const float4*)pj1;
    } else { f1i = make_float4(0,0,0,0); f1j = make_float4(0,0,0,0); }
    pi1 += 2*HW_; pj1 += 2*HW_;
  };
  auto stage_write = [&]() {
    if (val0) { *(float4*)&sm[lds0] = f0i; *(float4*)&sm[lds0 + OFF_J] = f0j; }
    if (val1) { *(float4*)&sm[lds1] = f1i; *(float4*)&sm[lds1 + OFF_J] = f1j; }
  };

  // ---------- ring + cc for macro mu (reads hsum bufs) ----------
  auto ring_cc = [&](int mu) {
    float nA[5], nB[5];
    #pragma unroll
    for (int f = 0; f < 5; ++f) { nA[f] = sm[hbA + f*HFS]; nB[f] = sm[hbB + f*HFS]; }
    float SA[5], SB[5];
    #pragma unroll
    for (int f = 0; f < 5; ++f) {
      SA[f] = S[f]  + nA[f] - ring[f][8];
      SB[f] = SA[f] + nB[f] - ring[f][7];
      S[f]  = SB[f];
      #pragma unroll
      for (int k = 8; k >= 2; --k) ring[f][k] = ring[f][k-2];
      ring[f][1] = nA[f]; ring[f][0] = nB[f];
    }
    if (mu >= 4) {
      {
        const float cr = SA[4] - SA[0]*SA[1]*W3I;
        const float vi = SA[2] - SA[0]*SA[0]*W3I;
        const float vj = SA[3] - SA[1]*SA[1]*W3I;
        acc += cr*cr * RCP(vi*vj + 1e-5f);
      }
      {
        const float cr = SB[4] - SB[0]*SB[1]*W3I;
        const float vi = SB[2] - SB[0]*SB[0]*W3I;
        const float vj = SB[3] - SB[1]*SB[1]*W3I;
        acc += cr*cr * RCP(vi*vj + 1e-5f);
      }
    }
  };

  fetch(d_lo - 4);        // macro 0's slices
  __syncthreads();        // zero-init visible
  stage_write();          // macro 0 raw
  __syncthreads();        // raw 0 ready

  int sA = d_lo - 4;
  for (int m = 0; m < NMAC; ++m, sA += 2) {
    if (m + 1 < NMAC) fetch(sA + 2);   // prefetch macro m+1 (regs)

    if (m > 0) ring_cc(m - 1);         // overlaps w-stage below

    // ---- w-stage: both slices, one 48-lane round ----
    if (wact) {
      const float4 a0 = *(const float4*)&sm[wrd];
      const float4 a1 = *(const float4*)&sm[wrd + 4];
      const float4 a2 = *(const float4*)&sm[wrd + 8];
      const float4 b0 = *(const float4*)&sm[wrd + OFF_J];
      const float4 b1 = *(const float4*)&sm[wrd + OFF_J + 4];
      const float4 b2 = *(const float4*)&sm[wrd + OFF_J + 8];
      const float wi[12] = {a0.x,a0.y,a0.z,a0.w,a1.x,a1.y,a1.z,a1.w,a2.x,a2.y,a2.z,a2.w};
      const float wj[12] = {b0.x,b0.y,b0.z,b0.w,b1.x,b1.y,b1.z,b1.w,b2.x,b2.y,b2.z,b2.w};
      SLIDEX(wi[k_],        0)
      SLIDEX(wj[k_],        1)
      SLIDEX(wi[k_]*wi[k_], 2)
      SLIDEX(wj[k_]*wj[k_], 3)
      SLIDEX(wi[k_]*wj[k_], 4)
    }
    LGKM0();   // wsum visible to own wave

    // ---- h-stage: 64-lane round + 16-lane remainder ----
    {
      auto hrun = [&](int rd, int wr) {
        float v[16];
        #pragma unroll
        for (int k = 0; k < 16; ++k) v[k] = sm[rd + k*20];
        float s = v[0]+v[1]+v[2]+v[3]+v[4]+v[5]+v[6]+v[7]+v[8];
        sm[wr] = s;
        #pragma unroll
        for (int j = 1; j < 8; ++j) { s += v[j+8] - v[j-1]; sm[wr + j*20] = s; }
      };
      hrun(h1rd, h1wr);
      if (hact2) hrun(h2rd, h2wr);
    }

    __syncthreads();                   // B1: raw reads of macro m done
    if (m + 1 < NMAC) stage_write();   // write macro m+1 raw
    __syncthreads();                   // B2: raw m+1 ready (drains lgkm too)
  }

  ring_cc(NMAC - 1);                   // last macro's slices

  // ---- block reduction -> single atomic ----
  float v = acc;
  #pragma unroll
  for (int off = 32; off > 0; off >>= 1)
    v += __shfl_down(v, off, 64);
  if (lane == 0) sm[OFF_RED + Q] = v;
  __syncthreads();
  if (tid == 0) {
    const float t = sm[OFF_RED] + sm[OFF_RED+1] + sm[OFF_RED+2] + sm[OFF_RED+3];
    atomicAdd(out, -t / NTOT);
  }
}

extern "C" void kernel_launch(void* const* d_in, const int* in_sizes, int n_in,
                              void* d_out, int out_size, void* d_ws, size_t ws_size,
                              hipStream_t stream) {
  const float* J = (const float*)d_in[0];  // y_pred
  const float* I = (const float*)d_in[1];  // y_true (cc symmetric in I,J)
  float* outp = (float*)d_out;
  hipMemsetAsync(d_out, 0, sizeof(float), stream);
  dim3 grid(W_/16, H_/16, B_*4);           // 10 x 12 x 8 = 960 blocks
  ncc_fused<<<grid, dim3(256), 0, stream>>>(I, J, outp);
}

// Round 6
// 151.349 us; speedup vs baseline: 1.1537x; 1.1537x over previous
//
#include <hip/hip_runtime.h>
#include <hip/hip_fp16.h>

// NCC loss, fully fused, R6: fp16 (half2) intermediates for wsum/hsum.
// R4 2-barrier macro structure + R5 lane-balance (48-lane w-round, shift-by-2
// ring). w-stage packs 4 fp32 sums -> b64 half2x2 write; h-stage does 2 w-cols
// per lane with packed __hadd2/__hsub2; ring reads half2 + extracts own half.
// Row strides 10 dw (bank-tiling), field strides = 6 mod 32. LDS 27.0 KB.
// Vols: [B=2][D=160][H=192][W=160] fp32. Out: scalar -mean(cc).

#define B_    2
#define D_    160
#define H_    192
#define W_    160
#define HW_   (H_*W_)
#define SSTR  28
#define SSLC  (24*SSTR)            // 672
#define OFF_J (2*SSLC)             // 1344: raw J slices base
#define OFF_WS 2688                // end of raw region
#define WROW  10                   // wsum row stride (dw = half2 units)
#define WSLC2 240                  // wsum slice stride (24*10)
#define WFS2  486                  // wsum field stride (2*240+6), mod 32 = 6
#define OFF_HS (OFF_WS + 5*WFS2)   // 5118
#define HROW  10
#define HSLC2 160                  // hsum slice stride (16*10)
#define HFS2  326                  // hsum field stride (2*160+6), mod 32 = 6
#define OFF_RED (OFF_HS + 5*HFS2)  // 6748
#define SMEM_TOT (OFF_RED + 8)     // 6756 dw = 27.0 KB -> grid-bound occupancy
#define DC    40
#define NMAC  24                   // (DC+8)/2
#define W3I   (1.0f/729.0f)
#define NTOT  9830400.0f

#if __has_builtin(__builtin_amdgcn_rcpf)
#define RCP(x) __builtin_amdgcn_rcpf(x)
#else
#define RCP(x) (1.0f/(x))
#endif

#define LGKM0() asm volatile("s_waitcnt lgkmcnt(0)" ::: "memory")

struct __align__(8) Half2x2 { __half2 a, b; };

// sliding 9-window along w: 12 inputs -> 4 outputs, packed to half2x2 (b64)
#define SLIDEX(EXPR, F) { \
  float v_[12]; \
  _Pragma("unroll") for (int k_ = 0; k_ < 12; ++k_) { v_[k_] = (EXPR); } \
  float s_ = v_[0]+v_[1]+v_[2]+v_[3]+v_[4]+v_[5]+v_[6]+v_[7]+v_[8]; \
  float4 o_; o_.x = s_; s_ += v_[9]-v_[0]; o_.y = s_; \
  s_ += v_[10]-v_[1]; o_.z = s_; s_ += v_[11]-v_[2]; o_.w = s_; \
  Half2x2 pk_; pk_.a = __floats2half2_rn(o_.x, o_.y); \
  pk_.b = __floats2half2_rn(o_.z, o_.w); \
  *(Half2x2*)&sm[wwr + (F)*WFS2] = pk_; }

__global__ __launch_bounds__(256, 4) void ncc_fused(const float* __restrict__ gI,
                                                    const float* __restrict__ gJ,
                                                    float* __restrict__ out)
{
  __shared__ __align__(16) float sm[SMEM_TOT];
  const int tid  = threadIdx.x;
  const int lane = tid & 63;
  const int Q    = tid >> 6;           // wave id = w-quad owner
  const int w0   = blockIdx.x * 16;
  const int h0   = blockIdx.y * 16;
  const int bz   = blockIdx.z;
  const int bb   = bz >> 2;
  const int d_lo = (bz & 3) * DC;

  // zero raw region once; invalid-hw slots stay 0 = 'same' zero pad
  for (int i = tid; i < OFF_WS; i += 256) sm[i] = 0.f;

  // ---------- staging task precompute: 288 tasks = 2 slc x 24 r x 6 quads ----
  bool val0 = false, val1 = false;
  int  lds0 = 0, lds1 = 0, slc0 = 0, slc1 = 0;
  const float *pi0 = gI, *pj0 = gJ, *pi1 = gI, *pj1 = gJ;
  {
    const int tA = tid;
    const int tB = (tid >= 224) ? (tid + 32) : 512;  // wave 3 takes 256..287
    auto prep = [&](int t, bool& val, int& lo, int& slc,
                    const float*& pi, const float*& pj) {
      if (t >= 288) { val = false; return; }
      slc = t / 144;
      const int u = t - slc*144;
      const int r = u / 6, c = u - r*6;
      const int gh = h0 - 4 + r;
      const int gw = w0 - 4 + 4*c;
      val = ((unsigned)gh < (unsigned)H_) && (gw >= 0) && (gw + 3 < W_);
      lo  = slc*SSLC + r*SSTR + 4*c;
      const long off = ((long)(bb*D_ + (d_lo - 4 + slc))*H_ + gh)*(long)W_ + gw;
      pi = gI + off; pj = gJ + off;
    };
    prep(tA, val0, lds0, slc0, pi0, pj0);
    prep(tB, val1, lds1, slc1, pi1, pj1);
  }

  // ---------- w-stage: 48 lanes = 2 slices x 24 rows ----------
  const bool wact = (lane < 48);
  const int  wslc = (lane >= 24) ? 1 : 0;
  const int  wrow = lane - 24*wslc;
  const int  wrd  = wslc*SSLC + wrow*SSTR + 4*Q;            // +OFF_J for J
  const int  wwr  = OFF_WS + wslc*WSLC2 + wrow*WROW + 2*Q;  // + f*WFS2

  // ---------- h-stage: 40 pair-tasks = 2 slc x 5 f x 2 half x 2 wpair ----
  const bool hact = (lane < 40);
  int hrd = 0, hwr = 0;
  {
    const int t     = hact ? lane : 0;
    const int wpair = t & 1;
    const int f     = (t >> 1) % 5;
    const int half  = (t / 10) & 1;
    const int slc   = t / 20;
    hrd = OFF_WS + f*WFS2 + slc*WSLC2 + half*(8*WROW) + 2*Q + wpair;  // +k*WROW
    hwr = OFF_HS + f*HFS2 + slc*HSLC2 + half*(8*HROW) + 2*Q + wpair;  // +j*HROW
  }

  // ---------- ring: lane -> (rh = lane>>2, w = 4Q + (lane&3)) ----------
  const int rh = lane >> 2, rwq = lane & 3;
  const int hb  = OFF_HS + rh*HROW + 2*Q + (rwq >> 1);   // + f*HFS2 (+HSLC2 for B)
  const int sh16 = (rwq & 1) * 16;                       // half-select shift

  float ring[5][9], S[5];
  #pragma unroll
  for (int f = 0; f < 5; ++f) {
    S[f] = 0.f;
    #pragma unroll
    for (int k = 0; k < 9; ++k) ring[f][k] = 0.f;
  }
  float acc = 0.f;

  // ---------- global prefetch ----------
  float4 f0i = {0,0,0,0}, f0j = {0,0,0,0}, f1i = {0,0,0,0}, f1j = {0,0,0,0};
  auto fetch = [&](int sbase) {
    if (val0 && (unsigned)(sbase + slc0) < (unsigned)D_) {
      f0i = *(const float4*)pi0; f0j = *(const float4*)pj0;
    } else { f0i = make_float4(0,0,0,0); f0j = make_float4(0,0,0,0); }
    pi0 += 2*HW_; pj0 += 2*HW_;
    if (val1 && (unsigned)(sbase + slc1) < (unsigned)D_) {
      f1i = *(const float4*)pi1; f1j = *(const float4*)pj1;
    } else { f1i = make_float4(0,0,0,0); f1j = make_float4(0,0,0,0); }
    pi1 += 2*HW_; pj1 += 2*HW_;
  };
  auto stage_write = [&]() {
    if (val0) { *(float4*)&sm[lds0] = f0i; *(float4*)&sm[lds0 + OFF_J] = f0j; }
    if (val1) { *(float4*)&sm[lds1] = f1i; *(float4*)&sm[lds1 + OFF_J] = f1j; }
  };

  auto h2ext = [&](int addr) -> float {   // read half2 word, extract own half
    const unsigned u = *(const unsigned*)&sm[addr];
    return __half2float(__ushort_as_half((unsigned short)(u >> sh16)));
  };

  fetch(d_lo - 4);        // macro 0's slices
  __syncthreads();        // zero-init visible
  stage_write();          // macro 0 raw
  __syncthreads();        // raw 0 ready

  int sA = d_lo - 4;
  for (int m = 0; m < NMAC; ++m, sA += 2) {
    if (m + 1 < NMAC) fetch(sA + 2);   // prefetch macro m+1 into regs

    // ---- w-stage: both slices, one 48-lane round, packed half2 writes ----
    if (wact) {
      const float4 a0 = *(const float4*)&sm[wrd];
      const float4 a1 = *(const float4*)&sm[wrd + 4];
      const float4 a2 = *(const float4*)&sm[wrd + 8];
      const float4 b0 = *(const float4*)&sm[wrd + OFF_J];
      const float4 b1 = *(const float4*)&sm[wrd + OFF_J + 4];
      const float4 b2 = *(const float4*)&sm[wrd + OFF_J + 8];
      const float wi[12] = {a0.x,a0.y,a0.z,a0.w,a1.x,a1.y,a1.z,a1.w,a2.x,a2.y,a2.z,a2.w};
      const float wj[12] = {b0.x,b0.y,b0.z,b0.w,b1.x,b1.y,b1.z,b1.w,b2.x,b2.y,b2.z,b2.w};
      SLIDEX(wi[k_],        0)
      SLIDEX(wj[k_],        1)
      SLIDEX(wi[k_]*wi[k_], 2)
      SLIDEX(wj[k_]*wj[k_], 3)
      SLIDEX(wi[k_]*wj[k_], 4)
    }
    LGKM0();   // wsum visible to own wave

    // ---- h-stage: packed half2, 2 w-columns per lane, 40 lanes ----
    if (hact) {
      __half2 v[16];
      #pragma unroll
      for (int k = 0; k < 16; ++k) v[k] = *(const __half2*)&sm[hrd + k*WROW];
      __half2 s = __hadd2(v[0], v[1]);
      s = __hadd2(s, v[2]); s = __hadd2(s, v[3]); s = __hadd2(s, v[4]);
      s = __hadd2(s, v[5]); s = __hadd2(s, v[6]); s = __hadd2(s, v[7]);
      s = __hadd2(s, v[8]);
      *(__half2*)&sm[hwr] = s;
      #pragma unroll
      for (int j = 1; j < 8; ++j) {
        s = __hsub2(__hadd2(s, v[j+8]), v[j-1]);
        *(__half2*)&sm[hwr + j*HROW] = s;
      }
    }
    LGKM0();   // hsum visible to own wave

    // ---- d-ring (shift by 2) + cc ----
    {
      float nA[5], nB[5];
      #pragma unroll
      for (int f = 0; f < 5; ++f) {
        nA[f] = h2ext(hb + f*HFS2);
        nB[f] = h2ext(hb + f*HFS2 + HSLC2);
      }
      float SA[5], SB[5];
      #pragma unroll
      for (int f = 0; f < 5; ++f) {
        SA[f] = S[f]  + nA[f] - ring[f][8];
        SB[f] = SA[f] + nB[f] - ring[f][7];
        S[f]  = SB[f];
        #pragma unroll
        for (int k = 8; k >= 2; --k) ring[f][k] = ring[f][k-2];
        ring[f][1] = nA[f]; ring[f][0] = nB[f];
      }
      if (m >= 4) {
        {
          const float cr = SA[4] - SA[0]*SA[1]*W3I;
          const float vi = SA[2] - SA[0]*SA[0]*W3I;
          const float vj = SA[3] - SA[1]*SA[1]*W3I;
          acc += cr*cr * RCP(vi*vj + 1e-5f);
        }
        {
          const float cr = SB[4] - SB[0]*SB[1]*W3I;
          const float vi = SB[2] - SB[0]*SB[0]*W3I;
          const float vj = SB[3] - SB[1]*SB[1]*W3I;
          acc += cr*cr * RCP(vi*vj + 1e-5f);
        }
      }
    }

    __syncthreads();                   // B1: raw reads of macro m done
    if (m + 1 < NMAC) stage_write();   // write macro m+1 raw
    __syncthreads();                   // B2: raw m+1 ready (drains lgkm)
  }

  // ---- block reduction -> single atomic ----
  float v = acc;
  #pragma unroll
  for (int off = 32; off > 0; off >>= 1)
    v += __shfl_down(v, off, 64);
  if (lane == 0) sm[OFF_RED + Q] = v;
  __syncthreads();
  if (tid == 0) {
    const float t = sm[OFF_RED] + sm[OFF_RED+1] + sm[OFF_RED+2] + sm[OFF_RED+3];
    atomicAdd(out, -t / NTOT);
  }
}

extern "C" void kernel_launch(void* const* d_in, const int* in_sizes, int n_in,
                              void* d_out, int out_size, void* d_ws, size_t ws_size,
                              hipStream_t stream) {
  const float* J = (const float*)d_in[0];  // y_pred
  const float* I = (const float*)d_in[1];  // y_true (cc symmetric in I,J)
  float* outp = (float*)d_out;
  hipMemsetAsync(d_out, 0, sizeof(float), stream);
  dim3 grid(W_/16, H_/16, B_*4);           // 10 x 12 x 8 = 960 blocks
  ncc_fused<<<grid, dim3(256), 0, stream>>>(I, J, outp);
}